// Round 1
// baseline (968.060 us; speedup 1.0000x reference)
//
#include <hip/hip_runtime.h>
#include <math.h>

#define T_   4
#define B_   32
#define C_   512
#define N_   196
#define TB_  128            // T_*B_
#define M_   25088          // TB_*N_
#define BCN_ 3211264        // B_*C_*N_
#define OUT1_ 12845056      // T_*B_*C_*N_

// GEMM tiling
#define BM 128
#define BN 128
#define BK 16
#define TM 8
#define TN 8
#define AS_STRIDE 132       // BM+4: keeps rows 16B-aligned, kills A-transpose bank conflicts

// ---------------------------------------------------------------------------
// K0: fold BN (and out bias) into per-channel scale/shift
// ---------------------------------------------------------------------------
__global__ void bn_prep_kernel(
    const float* __restrict__ qg, const float* __restrict__ qb, const float* __restrict__ qm, const float* __restrict__ qv,
    const float* __restrict__ kg, const float* __restrict__ kb, const float* __restrict__ km, const float* __restrict__ kvr,
    const float* __restrict__ vg, const float* __restrict__ vb, const float* __restrict__ vm, const float* __restrict__ vv,
    const float* __restrict__ og, const float* __restrict__ ob, const float* __restrict__ om, const float* __restrict__ ov,
    const float* __restrict__ obias,
    float* __restrict__ scale_qkv, float* __restrict__ shift_qkv,
    float* __restrict__ scale_o,   float* __restrict__ shift_o)
{
    int i = blockIdx.x * 256 + threadIdx.x;
    if (i < 3 * C_) {
        int p = i >> 9, dl = i & 511;
        const float* g = (p == 0) ? qg : (p == 1) ? kg : vg;
        const float* b = (p == 0) ? qb : (p == 1) ? kb : vb;
        const float* m = (p == 0) ? qm : (p == 1) ? km : vm;
        const float* r = (p == 0) ? qv : (p == 1) ? kvr : vv;
        float sc = g[dl] / sqrtf(r[dl] + 1e-5f);
        scale_qkv[i] = sc;
        shift_qkv[i] = b[dl] - m[dl] * sc;
    }
    if (i < C_) {
        float sc = og[i] / sqrtf(ov[i] + 1e-5f);
        scale_o[i] = sc;
        // (acc + bias)*sc + (b - m*sc)  ->  acc*sc + (bias*sc + b - m*sc)
        shift_o[i] = ob[i] - om[i] * sc + obias[i] * sc;
    }
}

// ---------------------------------------------------------------------------
// K1: xs = lif(x); store spikes in [c, tb, n] layout (GEMM B-matrix layout)
// ---------------------------------------------------------------------------
__global__ void lif_x_kernel(const float* __restrict__ x, float* __restrict__ xs)
{
    int idx = blockIdx.x * 256 + threadIdx.x;
    if (idx >= BCN_) return;
    int n = idx % N_;
    int c = (idx / N_) % C_;
    int b = idx / (N_ * C_);
    float v = 0.f;
#pragma unroll
    for (int t = 0; t < T_; ++t) {
        float xv = x[(size_t)t * BCN_ + idx];
        v = v + (xv - v) * 0.5f;                // == v + (x-v)/2 exactly
        float s = (v >= 1.0f) ? 1.0f : 0.0f;
        xs[(size_t)c * M_ + (t * B_ + b) * N_ + n] = s;
        v = (s > 0.f) ? 0.f : v;
    }
}

// ---------------------------------------------------------------------------
// K2/K6: tiled fp32 GEMM  C[dg, m] = sum_c W[dg, c] * Bmat[c, m]  (+BN epilogue)
// FINAL=false: dg in [0,1536) over {q,k,v} weights -> pre_all, scale/shift applied
// FINAL=true : dg in [0,512) out_w -> (acc*sc + sh) + identity, scatter to [tb,d,n]
// ---------------------------------------------------------------------------
template <bool FINAL>
__global__ __launch_bounds__(256)
void gemm_kernel(const float* __restrict__ wq, const float* __restrict__ wk,
                 const float* __restrict__ wv,
                 const float* __restrict__ Bmat,
                 const float* __restrict__ scale, const float* __restrict__ shift,
                 const float* __restrict__ xident,
                 float* __restrict__ out)
{
    const int bx = blockIdx.x;          // m tile (196)
    const int by = blockIdx.y;          // d tile
    const int tid = threadIdx.x;
    const int tx = tid & 15;
    const int ty = tid >> 4;

    __shared__ float As[BK * AS_STRIDE];
    __shared__ float Bs[BK * BN];

    const int dg0 = by * BM;
    const float* wsel;
    int dl0;
    if (FINAL) { wsel = wq; dl0 = dg0; }
    else {
        int p = dg0 >> 9;
        wsel = (p == 0) ? wq : (p == 1) ? wk : wv;
        dl0 = dg0 & 511;
    }
    const int m0 = bx * BN;

    float acc[TM][TN];
#pragma unroll
    for (int i = 0; i < TM; ++i)
#pragma unroll
        for (int j = 0; j < TN; ++j) acc[i][j] = 0.f;

    for (int k0 = 0; k0 < C_; k0 += BK) {
        __syncthreads();
        // stage A tile (BM x BK), store transposed As[kk][row]
#pragma unroll
        for (int r = 0; r < 2; ++r) {
            int l = tid + r * 256;              // 0..511
            int c4  = (l & 3) * 4;
            int row = l >> 2;
            float4 f = *reinterpret_cast<const float4*>(
                &wsel[(size_t)(dl0 + row) * C_ + k0 + c4]);
            As[(c4 + 0) * AS_STRIDE + row] = f.x;
            As[(c4 + 1) * AS_STRIDE + row] = f.y;
            As[(c4 + 2) * AS_STRIDE + row] = f.z;
            As[(c4 + 3) * AS_STRIDE + row] = f.w;
        }
        // stage B tile (BK x BN), row-major
#pragma unroll
        for (int r = 0; r < 2; ++r) {
            int l = tid + r * 256;
            int m4 = (l & 31) * 4;
            int kk = l >> 5;
            float4 f = *reinterpret_cast<const float4*>(
                &Bmat[(size_t)(k0 + kk) * M_ + m0 + m4]);
            *reinterpret_cast<float4*>(&Bs[kk * BN + m4]) = f;
        }
        __syncthreads();
#pragma unroll
        for (int kk = 0; kk < BK; ++kk) {
            float a[TM], b[TN];
            float4 a0 = *reinterpret_cast<const float4*>(&As[kk * AS_STRIDE + ty * TM]);
            float4 a1 = *reinterpret_cast<const float4*>(&As[kk * AS_STRIDE + ty * TM + 4]);
            a[0]=a0.x; a[1]=a0.y; a[2]=a0.z; a[3]=a0.w;
            a[4]=a1.x; a[5]=a1.y; a[6]=a1.z; a[7]=a1.w;
            float4 b0 = *reinterpret_cast<const float4*>(&Bs[kk * BN + tx * TN]);
            float4 b1 = *reinterpret_cast<const float4*>(&Bs[kk * BN + tx * TN + 4]);
            b[0]=b0.x; b[1]=b0.y; b[2]=b0.z; b[3]=b0.w;
            b[4]=b1.x; b[5]=b1.y; b[6]=b1.z; b[7]=b1.w;
#pragma unroll
            for (int i = 0; i < TM; ++i)
#pragma unroll
                for (int j = 0; j < TN; ++j)
                    acc[i][j] = fmaf(a[i], b[j], acc[i][j]);
        }
    }

#pragma unroll
    for (int i = 0; i < TM; ++i) {
        int dg = dg0 + ty * TM + i;
        float sc = scale[dg];
        float sh = shift[dg];
        if (!FINAL) {
#pragma unroll
            for (int j4 = 0; j4 < TN; j4 += 4) {
                float4 o;
                o.x = fmaf(acc[i][j4 + 0], sc, sh);
                o.y = fmaf(acc[i][j4 + 1], sc, sh);
                o.z = fmaf(acc[i][j4 + 2], sc, sh);
                o.w = fmaf(acc[i][j4 + 3], sc, sh);
                *reinterpret_cast<float4*>(&out[(size_t)dg * M_ + m0 + tx * TN + j4]) = o;
            }
        } else {
#pragma unroll
            for (int j = 0; j < TN; ++j) {
                int m = m0 + tx * TN + j;
                int tb = m / N_;
                int n  = m - tb * N_;
                size_t addr = (size_t)tb * (C_ * N_) + (size_t)dg * N_ + n;
                out[addr] = fmaf(acc[i][j], sc, sh) + xident[addr];
            }
        }
    }
}

// ---------------------------------------------------------------------------
// K3: in-place LIF over t on pre_all [1536, TB_, N_]  (pre -> spikes)
// ---------------------------------------------------------------------------
__global__ void lif_qkv_kernel(float* __restrict__ pre)
{
    int idx = blockIdx.x * 256 + threadIdx.x;   // over 1536*B_*N_
    if (idx >= 3 * C_ * B_ * N_) return;
    int n  = idx % N_;
    int b  = (idx / N_) % B_;
    int dg = idx / (N_ * B_);
    float* base = pre + (size_t)dg * M_ + b * N_ + n;
    float v = 0.f;
#pragma unroll
    for (int t = 0; t < T_; ++t) {
        float y = base[t * (B_ * N_)];
        v = v + (y - v) * 0.5f;
        float s = (v >= 1.0f) ? 1.0f : 0.0f;
        base[t * (B_ * N_)] = s;
        v = (s > 0.f) ? 0.f : v;
    }
}

// ---------------------------------------------------------------------------
// K4: kv[t,b,c] = sum_n k_s*v_s  (exact int), then LIF over t -> kv spikes
// one wave per (b,c)
// ---------------------------------------------------------------------------
__global__ void kv_kernel(const float* __restrict__ ks, const float* __restrict__ vs,
                          float* __restrict__ kvs)
{
    int gtid = blockIdx.x * 256 + threadIdx.x;
    int wid  = gtid >> 6;                // 0 .. B_*C_-1
    int lane = gtid & 63;
    int c = wid % C_;
    int b = wid / C_;
    const float* kb = ks + (size_t)c * M_ + b * N_;
    const float* vb = vs + (size_t)c * M_ + b * N_;
    float v = 0.f;
#pragma unroll
    for (int t = 0; t < T_; ++t) {
        float s = 0.f;
        for (int n = lane; n < N_; n += 64)
            s += kb[t * (B_ * N_) + n] * vb[t * (B_ * N_) + n];
#pragma unroll
        for (int off = 32; off; off >>= 1) s += __shfl_xor(s, off);
        v = v + (s - v) * 0.5f;
        float sp = (v >= 1.0f) ? 1.0f : 0.0f;
        if (lane == 0) kvs[(t * B_ + b) * C_ + c] = sp;
        v = (sp > 0.f) ? 0.f : v;
    }
}

// ---------------------------------------------------------------------------
// K5: y = q_s * kv_s (in place on q region of pre_all)
// ---------------------------------------------------------------------------
__global__ void muly_kernel(float* __restrict__ qs, const float* __restrict__ kvs)
{
    int idx = blockIdx.x * 256 + threadIdx.x;   // over C_*M_
    if (idx >= C_ * M_) return;
    int m = idx % M_;
    int c = idx / M_;
    int tb = m / N_;
    qs[idx] *= kvs[tb * C_ + c];
}

// ---------------------------------------------------------------------------
// K7: vh[t,b,h,n,hd] = v_s[h*64+hd, tb, n]   (coalesced writes)
// ---------------------------------------------------------------------------
__global__ void vh_kernel(const float* __restrict__ vs, float* __restrict__ out2)
{
    int idx = blockIdx.x * 256 + threadIdx.x;   // over OUT1_
    if (idx >= OUT1_) return;
    int d  = idx & 63;
    int n  = (idx >> 6) % N_;
    int h  = (idx / (64 * N_)) & 7;
    int tb = idx / (64 * N_ * 8);
    out2[idx] = vs[(size_t)(h * 64 + d) * M_ + tb * N_ + n];
}

// ---------------------------------------------------------------------------
extern "C" void kernel_launch(void* const* d_in, const int* in_sizes, int n_in,
                              void* d_out, int out_size, void* d_ws, size_t ws_size,
                              hipStream_t stream)
{
    const float* x    = (const float*)d_in[0];
    const float* q_w  = (const float*)d_in[1];
    const float* k_w  = (const float*)d_in[2];
    const float* v_w  = (const float*)d_in[3];
    const float* o_w  = (const float*)d_in[4];
    const float* o_b  = (const float*)d_in[5];
    const float* qg = (const float*)d_in[6],  *qb = (const float*)d_in[7],
               *qm = (const float*)d_in[8],  *qv = (const float*)d_in[9];
    const float* kg = (const float*)d_in[10], *kb = (const float*)d_in[11],
               *km = (const float*)d_in[12], *kv = (const float*)d_in[13];
    const float* vg = (const float*)d_in[14], *vb = (const float*)d_in[15],
               *vm = (const float*)d_in[16], *vv = (const float*)d_in[17];
    const float* og = (const float*)d_in[18], *ob = (const float*)d_in[19],
               *om = (const float*)d_in[20], *ov = (const float*)d_in[21];

    float* out1 = (float*)d_out;
    float* out2 = out1 + OUT1_;
    float* xs   = out2;                       // out2 region doubles as xs scratch

    float* pre    = (float*)d_ws;             // [1536, M_] fp32 (q|k|v)
    float* kvs    = pre + (size_t)3 * C_ * M_; // [T_,B_,C_]
    float* sc_qkv = kvs + T_ * B_ * C_;        // 1536
    float* sh_qkv = sc_qkv + 3 * C_;
    float* sc_o   = sh_qkv + 3 * C_;           // 512
    float* sh_o   = sc_o + C_;

    bn_prep_kernel<<<8, 256, 0, stream>>>(qg, qb, qm, qv, kg, kb, km, kv,
                                          vg, vb, vm, vv, og, ob, om, ov, o_b,
                                          sc_qkv, sh_qkv, sc_o, sh_o);

    lif_x_kernel<<<BCN_ / 256, 256, 0, stream>>>(x, xs);

    gemm_kernel<false><<<dim3(M_ / BN, (3 * C_) / BM), 256, 0, stream>>>(
        q_w, k_w, v_w, xs, sc_qkv, sh_qkv, nullptr, pre);

    lif_qkv_kernel<<<(3 * C_ * B_ * N_) / 256, 256, 0, stream>>>(pre);

    kv_kernel<<<(B_ * C_) / 4, 256, 0, stream>>>(
        pre + (size_t)C_ * M_, pre + (size_t)2 * C_ * M_, kvs);

    muly_kernel<<<(C_ * M_) / 256, 256, 0, stream>>>(pre, kvs);

    gemm_kernel<true><<<dim3(M_ / BN, C_ / BM), 256, 0, stream>>>(
        o_w, o_w, o_w, pre, sc_o, sh_o, x, out1);

    vh_kernel<<<OUT1_ / 256, 256, 0, stream>>>(pre + (size_t)2 * C_ * M_, out2);
}

// Round 2
// 562.781 us; speedup vs baseline: 1.7201x; 1.7201x over previous
//
#include <hip/hip_runtime.h>
#include <math.h>

#define T_   4
#define B_   32
#define C_   512
#define N_   196
#define TB_  128
#define M_   25088          // TB_*N_
#define BCN_ 3211264        // B_*C_*N_
#define OUT1_ 12845056      // T_*B_*C_*N_

typedef __attribute__((ext_vector_type(8))) __bf16 bf16x8;
typedef __attribute__((ext_vector_type(4))) float  f32x4;

__device__ __forceinline__ unsigned short f2bf(float f) {
    unsigned int u = __float_as_uint(f);
    u = u + 0x7FFFu + ((u >> 16) & 1u);      // RN-even
    return (unsigned short)(u >> 16);
}
__device__ __forceinline__ float bf2f(unsigned short h) {
    return __uint_as_float(((unsigned int)h) << 16);
}

#define GL2LDS(gp, lp) \
    __builtin_amdgcn_global_load_lds((const __attribute__((address_space(1))) void*)(gp), \
                                     (__attribute__((address_space(3))) void*)(lp), 16, 0, 0)

// ---------------------------------------------------------------------------
// K0: fold BN (and out bias) into per-channel scale/shift
// ---------------------------------------------------------------------------
__global__ void bn_prep_kernel(
    const float* __restrict__ qg, const float* __restrict__ qb, const float* __restrict__ qm, const float* __restrict__ qv,
    const float* __restrict__ kg, const float* __restrict__ kb, const float* __restrict__ km, const float* __restrict__ kvr,
    const float* __restrict__ vg, const float* __restrict__ vb, const float* __restrict__ vm, const float* __restrict__ vv,
    const float* __restrict__ og, const float* __restrict__ ob, const float* __restrict__ om, const float* __restrict__ ov,
    const float* __restrict__ obias,
    float* __restrict__ scale_qkv, float* __restrict__ shift_qkv,
    float* __restrict__ scale_o,   float* __restrict__ shift_o)
{
    int i = blockIdx.x * 256 + threadIdx.x;
    if (i < 3 * C_) {
        int p = i >> 9, dl = i & 511;
        const float* g = (p == 0) ? qg : (p == 1) ? kg : vg;
        const float* b = (p == 0) ? qb : (p == 1) ? kb : vb;
        const float* m = (p == 0) ? qm : (p == 1) ? km : vm;
        const float* r = (p == 0) ? qv : (p == 1) ? kvr : vv;
        float sc = g[dl] / sqrtf(r[dl] + 1e-5f);
        scale_qkv[i] = sc;
        shift_qkv[i] = b[dl] - m[dl] * sc;
    }
    if (i < C_) {
        float sc = og[i] / sqrtf(ov[i] + 1e-5f);
        scale_o[i] = sc;
        shift_o[i] = ob[i] - om[i] * sc + obias[i] * sc;
    }
}

// ---------------------------------------------------------------------------
// K0b: exact 3-way bf16 split of qkv weights -> wsplit[1536][3][512],
//      2-way split of out weights -> osplit[512][2][512]
// ---------------------------------------------------------------------------
__global__ void split_kernel(const float* __restrict__ qw, const float* __restrict__ kw,
                             const float* __restrict__ vw, const float* __restrict__ ow,
                             unsigned short* __restrict__ wsplit, unsigned short* __restrict__ osplit)
{
    int i = blockIdx.x * 256 + threadIdx.x;      // 1536*512
    int d = i >> 9, c = i & 511;
    const float* src = (d < 512) ? qw : (d < 1024) ? kw : vw;
    float wv = src[(d & 511) * 512 + c];
    unsigned short h = f2bf(wv);
    float r1 = wv - bf2f(h);
    unsigned short mm = f2bf(r1);
    float r2 = r1 - bf2f(mm);
    unsigned short l = f2bf(r2);                 // exact: h+m+l == wv
    wsplit[((size_t)d * 3 + 0) * 512 + c] = h;
    wsplit[((size_t)d * 3 + 1) * 512 + c] = mm;
    wsplit[((size_t)d * 3 + 2) * 512 + c] = l;
    if (d < 512) {
        float w2 = ow[d * 512 + c];
        unsigned short h2 = f2bf(w2);
        float rr = w2 - bf2f(h2);
        unsigned short m2 = f2bf(rr);
        osplit[((size_t)d * 2 + 0) * 512 + c] = h2;
        osplit[((size_t)d * 2 + 1) * 512 + c] = m2;
    }
}

// ---------------------------------------------------------------------------
// K1: xs = lif(x), transposed to [m][c] bf16 spikes via LDS tile
// grid (ntile=4, ctile=8, b=32), block 256
// ---------------------------------------------------------------------------
__global__ __launch_bounds__(256)
void lifx_kernel(const float* __restrict__ x, unsigned short* __restrict__ xs)
{
    __shared__ unsigned short tile[64 * 66];
    const int tid = threadIdx.x;
    const int b = blockIdx.z, c0 = blockIdx.y * 64, n0 = blockIdx.x * 64;
    const int j = tid & 63, w = tid >> 6;
    const bool nok = (n0 + j) < N_;
    float v[16];
#pragma unroll
    for (int r = 0; r < 16; ++r) v[r] = 0.f;
    for (int t = 0; t < T_; ++t) {
        const float* xb = x + ((size_t)((t * B_ + b) * C_ + c0)) * N_ + n0 + j;
#pragma unroll
        for (int r = 0; r < 16; ++r) {
            int i = w * 16 + r;
            float xv = nok ? xb[(size_t)i * N_] : 0.f;
            v[r] = v[r] + (xv - v[r]) * 0.5f;           // exact form from round 1
            bool s = (v[r] >= 1.0f);
            tile[j * 66 + i] = s ? 0x3F80 : 0;
            if (s) v[r] = 0.f;
        }
        __syncthreads();
#pragma unroll
        for (int p = 0; p < 2; ++p) {
            int w2 = tid + p * 256;
            int jj = w2 >> 3, ck = w2 & 7;
            if (n0 + jj < N_) {
                const unsigned int* src = reinterpret_cast<const unsigned int*>(&tile[jj * 66 + ck * 8]);
                uint4 dv; dv.x = src[0]; dv.y = src[1]; dv.z = src[2]; dv.w = src[3];
                size_t m = (size_t)(t * B_ + b) * N_ + n0 + jj;
                *reinterpret_cast<uint4*>(&xs[m * 512 + c0 + ck * 8]) = dv;
            }
        }
        __syncthreads();
    }
}

// ---------------------------------------------------------------------------
// K2/K6: MFMA bf16 GEMM with NSPLIT-way split weights (exact for NSPLIT=3).
// D[d][m] = sum_s sum_c Ws[d][c]*S[m][c].  128x128 tile, BK=32, 4 waves 2x2.
// FINAL=false: out = pre[dg][m] fp32 with BN scale/shift.
// FINAL=true : out1[tb][d][n] = acc*sc+sh + identity
// ---------------------------------------------------------------------------
template<int NSPLIT, bool FINAL>
__global__ __launch_bounds__(256)
void mfma_gemm(const unsigned short* __restrict__ A,   // [D][NSPLIT*512] bf16
               const unsigned short* __restrict__ Bm,  // [M][512] bf16
               const float* __restrict__ scale, const float* __restrict__ shift,
               const float* __restrict__ xid, float* __restrict__ out)
{
    __shared__ unsigned short As[NSPLIT * 4096];   // [s][128 d][32 k]
    __shared__ unsigned short Bs[4096];            // [128 m][32 k]
    const int tid = threadIdx.x, wid = tid >> 6, lane = tid & 63;
    const int d0 = blockIdx.y * 128, m0 = blockIdx.x * 128;
    const int dw = (wid >> 1) * 64, mw = (wid & 1) * 64;
    const int row16 = lane & 15, quad = lane >> 4;
    const int r4 = lane >> 2, kc = lane & 3;

    f32x4 acc[4][4] = {};

    for (int k0 = 0; k0 < 512; k0 += 32) {
        __syncthreads();
        // stage A tile: NSPLIT*8 issues of 1KB (16 rows x 64B)
        for (int q = wid; q < NSPLIT * 8; q += 4) {
            int s = q >> 3, it = q & 7;
            const unsigned short* g = A + ((size_t)((d0 + it * 16 + r4) * NSPLIT + s) * 512 + k0 + kc * 8);
            GL2LDS(g, &As[s * 4096 + it * 512]);
        }
        // stage B tile: 8 issues
        for (int q = wid; q < 8; q += 4) {
            const unsigned short* g = Bm + ((size_t)(m0 + q * 16 + r4) * 512 + k0 + kc * 8);
            GL2LDS(g, &Bs[q * 512]);
        }
        __syncthreads();

        bf16x8 bfr[4];
#pragma unroll
        for (int j = 0; j < 4; ++j)
            bfr[j] = *reinterpret_cast<const bf16x8*>(&Bs[(mw + j * 16 + row16) * 32 + quad * 8]);
#pragma unroll
        for (int i = 0; i < 4; ++i) {
#pragma unroll
            for (int s = 0; s < NSPLIT; ++s) {
                bf16x8 afr = *reinterpret_cast<const bf16x8*>(
                    &As[s * 4096 + (dw + i * 16 + row16) * 32 + quad * 8]);
#pragma unroll
                for (int j = 0; j < 4; ++j)
                    acc[i][j] = __builtin_amdgcn_mfma_f32_16x16x32_bf16(afr, bfr[j], acc[i][j], 0, 0, 0);
            }
        }
    }

#pragma unroll
    for (int j = 0; j < 4; ++j) {
        int m = m0 + mw + j * 16 + row16;
        int tb = 0, n = 0;
        if (FINAL) { tb = m / N_; n = m - tb * N_; }
#pragma unroll
        for (int i = 0; i < 4; ++i) {
            int d = d0 + dw + i * 16 + quad * 4;
            f32x4 a = acc[i][j];
#pragma unroll
            for (int r = 0; r < 4; ++r) {
                float val = fmaf(a[r], scale[d + r], shift[d + r]);
                if (!FINAL) {
                    out[(size_t)(d + r) * M_ + m] = val;
                } else {
                    size_t ad = (size_t)tb * (C_ * N_) + (size_t)(d + r) * N_ + n;
                    out[ad] = val + xid[ad];
                }
            }
        }
    }
}

// ---------------------------------------------------------------------------
// K3: in-place LIF over t on pre_all [1536, TB_, N_]  (pre -> fp32 spikes)
// ---------------------------------------------------------------------------
__global__ void lif_qkv_kernel(float* __restrict__ pre)
{
    int idx = blockIdx.x * 256 + threadIdx.x;
    if (idx >= 3 * C_ * B_ * N_) return;
    int n  = idx % N_;
    int b  = (idx / N_) % B_;
    int dg = idx / (N_ * B_);
    float* base = pre + (size_t)dg * M_ + b * N_ + n;
    float v = 0.f;
#pragma unroll
    for (int t = 0; t < T_; ++t) {
        float y = base[t * (B_ * N_)];
        v = v + (y - v) * 0.5f;
        float s = (v >= 1.0f) ? 1.0f : 0.0f;
        base[t * (B_ * N_)] = s;
        v = (s > 0.f) ? 0.f : v;
    }
}

// ---------------------------------------------------------------------------
// K4: kv[t,b,c] = sum_n k_s*v_s (exact int), LIF over t -> kv spikes [tb][c]
// ---------------------------------------------------------------------------
__global__ void kv_kernel(const float* __restrict__ ks, const float* __restrict__ vs,
                          float* __restrict__ kvs)
{
    int gtid = blockIdx.x * 256 + threadIdx.x;
    int wid  = gtid >> 6;
    int lane = gtid & 63;
    int c = wid % C_;
    int b = wid / C_;
    const float* kb = ks + (size_t)c * M_ + b * N_;
    const float* vb = vs + (size_t)c * M_ + b * N_;
    float v = 0.f;
#pragma unroll
    for (int t = 0; t < T_; ++t) {
        float s = 0.f;
        for (int n = lane; n < N_; n += 64)
            s += kb[t * (B_ * N_) + n] * vb[t * (B_ * N_) + n];
#pragma unroll
        for (int off = 32; off; off >>= 1) s += __shfl_xor(s, off);
        v = v + (s - v) * 0.5f;
        float sp = (v >= 1.0f) ? 1.0f : 0.0f;
        if (lane == 0) kvs[(t * B_ + b) * C_ + c] = sp;
        v = (sp > 0.f) ? 0.f : v;
    }
}

// ---------------------------------------------------------------------------
// K5: y[m][c] = q_s[c][m] * kv_s[tb][c]  -> bf16 spikes, LDS transpose
// grid (ntile=4, ctile=8, tb=128), block 256
// ---------------------------------------------------------------------------
__global__ __launch_bounds__(256)
void muly_kernel(const float* __restrict__ qs, const float* __restrict__ kvs,
                 unsigned short* __restrict__ y)
{
    __shared__ unsigned short tile[64 * 66];
    const int tid = threadIdx.x;
    const int tb = blockIdx.z, c0 = blockIdx.y * 64, n0 = blockIdx.x * 64;
    const int j = tid & 63, w = tid >> 6;
    const bool nok = (n0 + j) < N_;
#pragma unroll
    for (int r = 0; r < 16; ++r) {
        int i = w * 16 + r;
        float qv = nok ? qs[(size_t)(c0 + i) * M_ + (size_t)tb * N_ + n0 + j] : 0.f;
        float kv = kvs[tb * C_ + c0 + i];
        tile[j * 66 + i] = (qv * kv != 0.f) ? 0x3F80 : 0;
    }
    __syncthreads();
#pragma unroll
    for (int p = 0; p < 2; ++p) {
        int w2 = tid + p * 256;
        int jj = w2 >> 3, ck = w2 & 7;
        if (n0 + jj < N_) {
            const unsigned int* src = reinterpret_cast<const unsigned int*>(&tile[jj * 66 + ck * 8]);
            uint4 dv; dv.x = src[0]; dv.y = src[1]; dv.z = src[2]; dv.w = src[3];
            size_t m = (size_t)tb * N_ + n0 + jj;
            *reinterpret_cast<uint4*>(&y[m * 512 + c0 + ck * 8]) = dv;
        }
    }
}

// ---------------------------------------------------------------------------
// K7: vh[t,b,h,n,hd] = v_s[h*64+hd, tb, n]
// ---------------------------------------------------------------------------
__global__ void vh_kernel(const float* __restrict__ vs, float* __restrict__ out2)
{
    int idx = blockIdx.x * 256 + threadIdx.x;
    if (idx >= OUT1_) return;
    int d  = idx & 63;
    int n  = (idx >> 6) % N_;
    int h  = (idx / (64 * N_)) & 7;
    int tb = idx / (64 * N_ * 8);
    out2[idx] = vs[(size_t)(h * 64 + d) * M_ + (size_t)tb * N_ + n];
}

// ---------------------------------------------------------------------------
extern "C" void kernel_launch(void* const* d_in, const int* in_sizes, int n_in,
                              void* d_out, int out_size, void* d_ws, size_t ws_size,
                              hipStream_t stream)
{
    const float* x    = (const float*)d_in[0];
    const float* q_w  = (const float*)d_in[1];
    const float* k_w  = (const float*)d_in[2];
    const float* v_w  = (const float*)d_in[3];
    const float* o_w  = (const float*)d_in[4];
    const float* o_b  = (const float*)d_in[5];
    const float* qg = (const float*)d_in[6],  *qb = (const float*)d_in[7],
               *qm = (const float*)d_in[8],  *qv = (const float*)d_in[9];
    const float* kg = (const float*)d_in[10], *kb = (const float*)d_in[11],
               *km = (const float*)d_in[12], *kv = (const float*)d_in[13];
    const float* vg = (const float*)d_in[14], *vb = (const float*)d_in[15],
               *vm = (const float*)d_in[16], *vv = (const float*)d_in[17];
    const float* og = (const float*)d_in[18], *ob = (const float*)d_in[19],
               *om = (const float*)d_in[20], *ov = (const float*)d_in[21];

    float* out1 = (float*)d_out;
    float* out2f = out1 + OUT1_;
    // out2 region doubles as scratch until vh_kernel (the last kernel) overwrites it
    unsigned short* xs     = (unsigned short*)out2f;        // [M][512] bf16; later aliased by y
    unsigned short* wsplit = xs + (size_t)M_ * 512;         // 1536*1536
    unsigned short* osplit = wsplit + (size_t)1536 * 1536;  // 512*1024

    float* pre = (float*)d_ws;                    // [1536][M] fp32
    float* kvs = pre + (size_t)3 * C_ * M_;       // [TB][C]
    float* scq = kvs + (size_t)TB_ * C_;
    float* shq = scq + 3 * C_;
    float* sco = shq + 3 * C_;
    float* sho = sco + C_;

    bn_prep_kernel<<<8, 256, 0, stream>>>(qg, qb, qm, qv, kg, kb, km, kv,
                                          vg, vb, vm, vv, og, ob, om, ov, o_b,
                                          scq, shq, sco, sho);

    split_kernel<<<(1536 * 512) / 256, 256, 0, stream>>>(q_w, k_w, v_w, o_w, wsplit, osplit);

    lifx_kernel<<<dim3(4, 8, 32), 256, 0, stream>>>(x, xs);

    mfma_gemm<3, false><<<dim3(196, 12), 256, 0, stream>>>(wsplit, xs, scq, shq, nullptr, pre);

    lif_qkv_kernel<<<(3 * C_ * B_ * N_) / 256, 256, 0, stream>>>(pre);

    kv_kernel<<<(B_ * C_) / 4, 256, 0, stream>>>(
        pre + (size_t)C_ * M_, pre + (size_t)2 * C_ * M_, kvs);

    muly_kernel<<<dim3(4, 8, 128), 256, 0, stream>>>(pre, kvs, xs /*reused as y*/);

    mfma_gemm<2, true><<<dim3(196, 4), 256, 0, stream>>>(osplit, xs, sco, sho, x, out1);

    vh_kernel<<<OUT1_ / 256, 256, 0, stream>>>(pre + (size_t)2 * C_ * M_, out2f);
}

// Round 4
// 504.025 us; speedup vs baseline: 1.9207x; 1.1166x over previous
//
#include <hip/hip_runtime.h>
#include <math.h>

#define T_   4
#define B_   32
#define C_   512
#define N_   196
#define TB_  128
#define M_   25088          // TB_*N_
#define BNP_ 6272           // B_*N_  (t-plane stride in m-space)
#define OUT1_ 12845056      // T_*B_*C_*N_

typedef unsigned short ushort_t;
typedef __attribute__((ext_vector_type(8))) __bf16 bf16x8;
typedef __attribute__((ext_vector_type(4))) float  f32x4;

__device__ __forceinline__ ushort_t f2bf(float f) {
    unsigned int u = __float_as_uint(f);
    u = u + 0x7FFFu + ((u >> 16) & 1u);      // RN-even
    return (ushort_t)(u >> 16);
}
__device__ __forceinline__ float bf2f(ushort_t h) {
    return __uint_as_float(((unsigned int)h) << 16);
}

#define GL2LDS(gp, lp) \
    __builtin_amdgcn_global_load_lds((const __attribute__((address_space(1))) void*)(gp), \
                                     (__attribute__((address_space(3))) void*)(lp), 16, 0, 0)

// ---------------------------------------------------------------------------
// K0: fold BN (and out bias) into per-channel scale/shift
// ---------------------------------------------------------------------------
__global__ void bn_prep_kernel(
    const float* __restrict__ qg, const float* __restrict__ qb, const float* __restrict__ qm, const float* __restrict__ qv,
    const float* __restrict__ kg, const float* __restrict__ kb, const float* __restrict__ km, const float* __restrict__ kvr,
    const float* __restrict__ vg, const float* __restrict__ vb, const float* __restrict__ vm, const float* __restrict__ vv,
    const float* __restrict__ og, const float* __restrict__ ob, const float* __restrict__ om, const float* __restrict__ ov,
    const float* __restrict__ obias,
    float* __restrict__ scale_qkv, float* __restrict__ shift_qkv,
    float* __restrict__ scale_o,   float* __restrict__ shift_o)
{
    int i = blockIdx.x * 256 + threadIdx.x;
    if (i < 3 * C_) {
        int p = i >> 9, dl = i & 511;
        const float* g = (p == 0) ? qg : (p == 1) ? kg : vg;
        const float* b = (p == 0) ? qb : (p == 1) ? kb : vb;
        const float* m = (p == 0) ? qm : (p == 1) ? km : vm;
        const float* r = (p == 0) ? qv : (p == 1) ? kvr : vv;
        float sc = g[dl] / sqrtf(r[dl] + 1e-5f);
        scale_qkv[i] = sc;
        shift_qkv[i] = b[dl] - m[dl] * sc;
    }
    if (i < C_) {
        float sc = og[i] / sqrtf(ov[i] + 1e-5f);
        scale_o[i] = sc;
        shift_o[i] = ob[i] - om[i] * sc + obias[i] * sc;
    }
}

// ---------------------------------------------------------------------------
// K0b: exact 3-way bf16 split of qkv weights -> wsplit[1536][3][512];
//      plain bf16 out weights -> osplit[512][512] (error ~7e-4 << 0.108 thr)
// ---------------------------------------------------------------------------
__global__ void split_kernel(const float* __restrict__ qw, const float* __restrict__ kw,
                             const float* __restrict__ vw, const float* __restrict__ ow,
                             ushort_t* __restrict__ wsplit, ushort_t* __restrict__ osplit)
{
    int i = blockIdx.x * 256 + threadIdx.x;      // 1536*512
    int d = i >> 9, c = i & 511;
    const float* src = (d < 512) ? qw : (d < 1024) ? kw : vw;
    float wv = src[(d & 511) * 512 + c];
    ushort_t h = f2bf(wv);
    float r1 = wv - bf2f(h);
    ushort_t mm = f2bf(r1);
    float r2 = r1 - bf2f(mm);
    ushort_t l = f2bf(r2);                       // h+m+l == wv (within 2^-26)
    wsplit[((size_t)d * 3 + 0) * 512 + c] = h;
    wsplit[((size_t)d * 3 + 1) * 512 + c] = mm;
    wsplit[((size_t)d * 3 + 2) * 512 + c] = l;
    if (d < 512)
        osplit[(size_t)d * 512 + c] = f2bf(ow[d * 512 + c]);
}

// ---------------------------------------------------------------------------
// K1: xs = lif(x), transposed to [m'][c] bf16 spikes, m' = (b*196+n)*4 + t
// grid (ntile=4, ctile=8, b=32), block 256
// ---------------------------------------------------------------------------
__global__ __launch_bounds__(256)
void lifx_kernel(const float* __restrict__ x, ushort_t* __restrict__ xs)
{
    __shared__ ushort_t tile[64 * 66];
    const int tid = threadIdx.x;
    const int b = blockIdx.z, c0 = blockIdx.y * 64, n0 = blockIdx.x * 64;
    const int j = tid & 63, w = tid >> 6;
    const bool nok = (n0 + j) < N_;
    float v[16];
#pragma unroll
    for (int r = 0; r < 16; ++r) v[r] = 0.f;
    for (int t = 0; t < T_; ++t) {
        const float* xb = x + ((size_t)((t * B_ + b) * C_ + c0)) * N_ + n0 + j;
#pragma unroll
        for (int r = 0; r < 16; ++r) {
            int i = w * 16 + r;
            float xv = nok ? xb[(size_t)i * N_] : 0.f;
            v[r] = v[r] + (xv - v[r]) * 0.5f;
            bool s = (v[r] >= 1.0f);
            tile[j * 66 + i] = s ? 0x3F80 : 0;
            if (s) v[r] = 0.f;
        }
        __syncthreads();
#pragma unroll
        for (int p = 0; p < 2; ++p) {
            int w2 = tid + p * 256;
            int jj = w2 >> 3, ck = w2 & 7;
            if (n0 + jj < N_) {
                const unsigned int* src = reinterpret_cast<const unsigned int*>(&tile[jj * 66 + ck * 8]);
                uint4 dv; dv.x = src[0]; dv.y = src[1]; dv.z = src[2]; dv.w = src[3];
                size_t mp = (size_t)(b * N_ + n0 + jj) * 4 + t;      // permuted row
                *reinterpret_cast<uint4*>(&xs[mp * 512 + c0 + ck * 8]) = dv;
            }
        }
        __syncthreads();
    }
}

// ---------------------------------------------------------------------------
// K2: qkv GEMM, MFMA bf16, 3-split exact weights, fused BN + LIF epilogue.
// Operand roles SWAPPED vs round 2: A-op = xs rows (m'), B-op = W rows (d)
// -> D[m'][d]: lane's 4 acc regs = t=0..3 of one (b,n). LIF is in-register.
// LDS staged in [chunk][row] blocks so fragment reads are base + lane*16B
// (zero bank conflicts). Stores bf16 spikes to spk[plane][m][512], m natural.
// ---------------------------------------------------------------------------
__global__ __launch_bounds__(256)
void qkv_gemm_lif(const ushort_t* __restrict__ W, const ushort_t* __restrict__ X,
                  const float* __restrict__ scale, const float* __restrict__ shift,
                  ushort_t* __restrict__ spk)
{
    __shared__ ushort_t Xs[4096];        // 8 blocks x [4 chunk][16 row][8]
    __shared__ ushort_t Ws[3 * 4096];
    const int tid = threadIdx.x, wid = tid >> 6, lane = tid & 63;
    const int m0 = blockIdx.x * 128;     // m' base
    const int d0 = blockIdx.y * 128;     // global d in [0,1536)
    const int mw = (wid & 1) * 64, dw = (wid >> 1) * 64;
    const int row16 = lane & 15, quad = lane >> 4;

    f32x4 acc[4][4] = {};                // [i: m'-block][j: d-block]

    for (int k0 = 0; k0 < 512; k0 += 32) {
        __syncthreads();
        // staging source mapping: lane -> (row = lane&15, chunk = lane>>4)
        for (int q = wid; q < 8; q += 4) {
            const ushort_t* g = X + (size_t)(m0 + q * 16 + row16) * 512 + k0 + quad * 8;
            GL2LDS(g, &Xs[q * 512]);
        }
        for (int q = wid; q < 24; q += 4) {
            int s = q >> 3, it = q & 7;
            const ushort_t* g = W + ((size_t)(d0 + it * 16 + row16) * 3 + s) * 512 + k0 + quad * 8;
            GL2LDS(g, &Ws[s * 4096 + it * 512]);
        }
        __syncthreads();

        bf16x8 xfr[4];
#pragma unroll
        for (int i = 0; i < 4; ++i)
            xfr[i] = *reinterpret_cast<const bf16x8*>(&Xs[((mw >> 4) + i) * 512 + lane * 8]);
#pragma unroll
        for (int s = 0; s < 3; ++s)
#pragma unroll
            for (int j = 0; j < 4; ++j) {
                bf16x8 wfr = *reinterpret_cast<const bf16x8*>(
                    &Ws[s * 4096 + ((dw >> 4) + j) * 512 + lane * 8]);
#pragma unroll
                for (int i = 0; i < 4; ++i)
                    acc[i][j] = __builtin_amdgcn_mfma_f32_16x16x32_bf16(xfr[i], wfr, acc[i][j], 0, 0, 0);
            }
    }

    // epilogue: BN, then LIF over t (= reg index), store bf16 spikes
    const int p = d0 >> 9;
    ushort_t* plane = spk + (size_t)p * ((size_t)M_ * 512);
#pragma unroll
    for (int i = 0; i < 4; ++i) {
        int bn = (m0 + mw + i * 16 + quad * 4) >> 2;      // same for all 4 regs
#pragma unroll
        for (int j = 0; j < 4; ++j) {
            int d = d0 + dw + j * 16 + row16;
            float sc = scale[d], sh = shift[d];
            int dl = d & 511;
            f32x4 a = acc[i][j];
            float p0 = fmaf(a[0], sc, sh);
            float p1 = fmaf(a[1], sc, sh);
            float p2 = fmaf(a[2], sc, sh);
            float p3 = fmaf(a[3], sc, sh);
            float v = p0 * 0.5f;                           // == 0 + (p0-0)*0.5
            bool s0 = (v >= 1.f); if (s0) v = 0.f;
            v = v + (p1 - v) * 0.5f;
            bool s1 = (v >= 1.f); if (s1) v = 0.f;
            v = v + (p2 - v) * 0.5f;
            bool s2 = (v >= 1.f); if (s2) v = 0.f;
            v = v + (p3 - v) * 0.5f;
            bool s3 = (v >= 1.f);
            ushort_t* b0 = plane + (size_t)bn * 512 + dl;
            b0[0]                          = s0 ? 0x3F80 : 0;
            b0[(size_t)BNP_ * 512]         = s1 ? 0x3F80 : 0;
            b0[(size_t)2 * BNP_ * 512]     = s2 ? 0x3F80 : 0;
            b0[(size_t)3 * BNP_ * 512]     = s3 ? 0x3F80 : 0;
        }
    }
}

// ---------------------------------------------------------------------------
// K3: kvpart[tb][c] = sum_n (k_s & v_s)  (exact integer count)
// ---------------------------------------------------------------------------
__global__ void kv_part_kernel(const ushort_t* __restrict__ ks, const ushort_t* __restrict__ vs,
                               float* __restrict__ kvpart)
{
    int tb = blockIdx.x >> 1;
    int c  = (blockIdx.x & 1) * 256 + threadIdx.x;
    const ushort_t* kb = ks + (size_t)tb * N_ * 512 + c;
    const ushort_t* vb = vs + (size_t)tb * N_ * 512 + c;
    int cnt = 0;
    for (int n = 0; n < N_; ++n)
        cnt += (kb[(size_t)n * 512] & vb[(size_t)n * 512]) ? 1 : 0;
    kvpart[tb * 512 + c] = (float)cnt;
}

// ---------------------------------------------------------------------------
// K4: LIF over t on kvpart -> kv spikes bf16 [tb][c]
// ---------------------------------------------------------------------------
__global__ void kv_lif_kernel(const float* __restrict__ kvpart, ushort_t* __restrict__ kvs)
{
    int i = blockIdx.x * 256 + threadIdx.x;      // 32*512
    if (i >= B_ * C_) return;
    int b = i >> 9, c = i & 511;
    float v = 0.f;
#pragma unroll
    for (int t = 0; t < T_; ++t) {
        float y = kvpart[((t * B_ + b) << 9) + c];
        v = v + (y - v) * 0.5f;
        bool s = (v >= 1.f);
        kvs[((t * B_ + b) << 9) + c] = s ? 0x3F80 : 0;
        if (s) v = 0.f;
    }
}

// ---------------------------------------------------------------------------
// K5: y[m][c] = q_s[m][c] & kvs[tb][c]   (pure AND of spike bit patterns)
// ---------------------------------------------------------------------------
__global__ void muly_kernel(const ushort_t* __restrict__ qs, const ushort_t* __restrict__ kvs,
                            ushort_t* __restrict__ y)
{
    int i = blockIdx.x * 256 + threadIdx.x;      // uint4 (8-short) units
    int m = i >> 6, cq = (i & 63) * 8;
    int tb = m / N_;
    uint4 q = *reinterpret_cast<const uint4*>(&qs[(size_t)m * 512 + cq]);
    uint4 k = *reinterpret_cast<const uint4*>(&kvs[(size_t)tb * 512 + cq]);
    uint4 o; o.x = q.x & k.x; o.y = q.y & k.y; o.z = q.z & k.z; o.w = q.w & k.w;
    *reinterpret_cast<uint4*>(&y[(size_t)m * 512 + cq]) = o;
}

// ---------------------------------------------------------------------------
// K6: out GEMM, round-2 orientation (A-op = weights rows d, B-op = y rows m),
// single bf16 weights, linear-swizzled LDS staging, BN+bias+identity epilogue.
// ---------------------------------------------------------------------------
__global__ __launch_bounds__(256)
void out_gemm(const ushort_t* __restrict__ A, const ushort_t* __restrict__ Bm,
              const float* __restrict__ scale, const float* __restrict__ shift,
              const float* __restrict__ xid, float* __restrict__ out)
{
    __shared__ ushort_t As[4096];
    __shared__ ushort_t Bs[4096];
    const int tid = threadIdx.x, wid = tid >> 6, lane = tid & 63;
    const int d0 = blockIdx.y * 128, m0 = blockIdx.x * 128;
    const int dw = (wid >> 1) * 64, mw = (wid & 1) * 64;
    const int row16 = lane & 15, quad = lane >> 4;

    f32x4 acc[4][4] = {};                // [i: d-block][j: m-block]

    for (int k0 = 0; k0 < 512; k0 += 32) {
        __syncthreads();
        for (int q = wid; q < 8; q += 4) {
            const ushort_t* g = A + (size_t)(d0 + q * 16 + row16) * 512 + k0 + quad * 8;
            GL2LDS(g, &As[q * 512]);
        }
        for (int q = wid; q < 8; q += 4) {
            const ushort_t* g = Bm + (size_t)(m0 + q * 16 + row16) * 512 + k0 + quad * 8;
            GL2LDS(g, &Bs[q * 512]);
        }
        __syncthreads();

        bf16x8 bfr[4];
#pragma unroll
        for (int j = 0; j < 4; ++j)
            bfr[j] = *reinterpret_cast<const bf16x8*>(&Bs[((mw >> 4) + j) * 512 + lane * 8]);
#pragma unroll
        for (int i = 0; i < 4; ++i) {
            bf16x8 afr = *reinterpret_cast<const bf16x8*>(&As[((dw >> 4) + i) * 512 + lane * 8]);
#pragma unroll
            for (int j = 0; j < 4; ++j)
                acc[i][j] = __builtin_amdgcn_mfma_f32_16x16x32_bf16(afr, bfr[j], acc[i][j], 0, 0, 0);
        }
    }

#pragma unroll
    for (int j = 0; j < 4; ++j) {
        int m = m0 + mw + j * 16 + row16;
        int tb = m / N_;
        int n  = m - tb * N_;
#pragma unroll
        for (int i = 0; i < 4; ++i) {
            int d = d0 + dw + i * 16 + quad * 4;
            f32x4 a = acc[i][j];
#pragma unroll
            for (int r = 0; r < 4; ++r) {
                float val = fmaf(a[r], scale[d + r], shift[d + r]);
                size_t ad = (size_t)tb * (C_ * N_) + (size_t)(d + r) * N_ + n;
                out[ad] = val + xid[ad];
            }
        }
    }
}

// ---------------------------------------------------------------------------
// K7: vh[t,b,h,n,hd] = v_s[m][c] — both sides c/d-fastest: coalesced copy+cast
// ---------------------------------------------------------------------------
__global__ void vh_kernel(const ushort_t* __restrict__ vs, float* __restrict__ out2)
{
    int i = blockIdx.x * 256 + threadIdx.x;      // 8-element units
    int d8 = (i & 7) * 8;
    int n  = (i >> 3) % N_;
    int ht = (i >> 3) / N_;                      // tb*8 + h
    int h  = ht & 7, tb = ht >> 3;
    uint4 sv = *reinterpret_cast<const uint4*>(&vs[((size_t)tb * N_ + n) * 512 + h * 64 + d8]);
    float4 f0, f1;
    f0.x = __uint_as_float(sv.x << 16); f0.y = __uint_as_float(sv.x & 0xFFFF0000u);
    f0.z = __uint_as_float(sv.y << 16); f0.w = __uint_as_float(sv.y & 0xFFFF0000u);
    f1.x = __uint_as_float(sv.z << 16); f1.y = __uint_as_float(sv.z & 0xFFFF0000u);
    f1.z = __uint_as_float(sv.w << 16); f1.w = __uint_as_float(sv.w & 0xFFFF0000u);
    float* dst = out2 + (size_t)i * 8;
    *reinterpret_cast<float4*>(dst)     = f0;
    *reinterpret_cast<float4*>(dst + 4) = f1;
}

// ---------------------------------------------------------------------------
extern "C" void kernel_launch(void* const* d_in, const int* in_sizes, int n_in,
                              void* d_out, int out_size, void* d_ws, size_t ws_size,
                              hipStream_t stream)
{
    const float* x    = (const float*)d_in[0];
    const float* q_w  = (const float*)d_in[1];
    const float* k_w  = (const float*)d_in[2];
    const float* v_w  = (const float*)d_in[3];
    const float* o_w  = (const float*)d_in[4];
    const float* o_b  = (const float*)d_in[5];
    const float* qg = (const float*)d_in[6],  *qb = (const float*)d_in[7],
               *qm = (const float*)d_in[8],  *qv = (const float*)d_in[9];
    const float* kg = (const float*)d_in[10], *kb = (const float*)d_in[11],
               *km = (const float*)d_in[12], *kv = (const float*)d_in[13];
    const float* vg = (const float*)d_in[14], *vb = (const float*)d_in[15],
               *vm = (const float*)d_in[16], *vv = (const float*)d_in[17];
    const float* og = (const float*)d_in[18], *ob = (const float*)d_in[19],
               *om = (const float*)d_in[20], *ov = (const float*)d_in[21];

    float* out1  = (float*)d_out;
    float* out2f = out1 + OUT1_;

    // out2 region doubles as scratch until vh_kernel (last) overwrites it
    ushort_t* xs     = (ushort_t*)out2f;                     // [M][512], m' order; later reused as y (m natural)
    ushort_t* wsplit = xs + (size_t)M_ * 512;                // 1536*3*512
    ushort_t* osplit = wsplit + (size_t)1536 * 3 * 512;      // 512*512

    // d_ws
    ushort_t* spk    = (ushort_t*)d_ws;                      // [3][M][512] bf16 spikes
    float*    kvpart = (float*)(spk + (size_t)3 * M_ * 512); // [TB][C]
    ushort_t* kvs    = (ushort_t*)(kvpart + TB_ * C_);       // [TB][C]
    float*    scq    = (float*)(kvs + TB_ * C_);
    float*    shq    = scq + 3 * C_;
    float*    sco    = shq + 3 * C_;
    float*    sho    = sco + C_;

    ushort_t* ksp = spk + (size_t)M_ * 512;
    ushort_t* vsp = spk + (size_t)2 * M_ * 512;

    bn_prep_kernel<<<8, 256, 0, stream>>>(qg, qb, qm, qv, kg, kb, km, kv,
                                          vg, vb, vm, vv, og, ob, om, ov, o_b,
                                          scq, shq, sco, sho);

    split_kernel<<<(1536 * 512) / 256, 256, 0, stream>>>(q_w, k_w, v_w, o_w, wsplit, osplit);

    lifx_kernel<<<dim3(4, 8, 32), 256, 0, stream>>>(x, xs);

    qkv_gemm_lif<<<dim3(196, 12), 256, 0, stream>>>(wsplit, xs, scq, shq, spk);

    kv_part_kernel<<<256, 256, 0, stream>>>(ksp, vsp, kvpart);

    kv_lif_kernel<<<64, 256, 0, stream>>>(kvpart, kvs);

    muly_kernel<<<(M_ * 64) / 256, 256, 0, stream>>>(spk, kvs, xs /* reused as y */);

    out_gemm<<<dim3(196, 4), 256, 0, stream>>>(osplit, xs, sco, sho, x, out1);

    vh_kernel<<<(OUT1_ / 8) / 256, 256, 0, stream>>>(vsp, out2f);
}

// Round 5
// 450.834 us; speedup vs baseline: 2.1473x; 1.1180x over previous
//
#include <hip/hip_runtime.h>
#include <math.h>

#define T_   4
#define B_   32
#define C_   512
#define N_   196
#define TB_  128
#define M_   25088          // TB_*N_
#define BNP_ 6272           // B_*N_  (t-plane stride in bn-space)
#define OUT1_ 12845056      // T_*B_*C_*N_

typedef unsigned short ushort_t;
typedef __attribute__((ext_vector_type(8)))  __bf16 bf16x8;
typedef __attribute__((ext_vector_type(16))) float  f32x16;

__device__ __forceinline__ ushort_t f2bf(float f) {
    unsigned int u = __float_as_uint(f);
    u = u + 0x7FFFu + ((u >> 16) & 1u);      // RN-even
    return (ushort_t)(u >> 16);
}
__device__ __forceinline__ float bf2f(ushort_t h) {
    return __uint_as_float(((unsigned int)h) << 16);
}

#define GL2LDS(gp, lp) \
    __builtin_amdgcn_global_load_lds((const __attribute__((address_space(1))) void*)(gp), \
                                     (__attribute__((address_space(3))) void*)(lp), 16, 0, 0)

// ---------------------------------------------------------------------------
// K0: fold BN (and out bias) into per-channel scale/shift
// ---------------------------------------------------------------------------
__global__ void bn_prep_kernel(
    const float* __restrict__ qg, const float* __restrict__ qb, const float* __restrict__ qm, const float* __restrict__ qv,
    const float* __restrict__ kg, const float* __restrict__ kb, const float* __restrict__ km, const float* __restrict__ kvr,
    const float* __restrict__ vg, const float* __restrict__ vb, const float* __restrict__ vm, const float* __restrict__ vv,
    const float* __restrict__ og, const float* __restrict__ ob, const float* __restrict__ om, const float* __restrict__ ov,
    const float* __restrict__ obias,
    float* __restrict__ scale_qkv, float* __restrict__ shift_qkv,
    float* __restrict__ scale_o,   float* __restrict__ shift_o)
{
    int i = blockIdx.x * 256 + threadIdx.x;
    if (i < 3 * C_) {
        int p = i >> 9, dl = i & 511;
        const float* g = (p == 0) ? qg : (p == 1) ? kg : vg;
        const float* b = (p == 0) ? qb : (p == 1) ? kb : vb;
        const float* m = (p == 0) ? qm : (p == 1) ? km : vm;
        const float* r = (p == 0) ? qv : (p == 1) ? kvr : vv;
        float sc = g[dl] / sqrtf(r[dl] + 1e-5f);
        scale_qkv[i] = sc;
        shift_qkv[i] = b[dl] - m[dl] * sc;
    }
    if (i < C_) {
        float sc = og[i] / sqrtf(ov[i] + 1e-5f);
        scale_o[i] = sc;
        shift_o[i] = ob[i] - om[i] * sc + obias[i] * sc;
    }
}

// ---------------------------------------------------------------------------
// K0b: exact 3-way bf16 split of qkv weights; plain bf16 out weights
// ---------------------------------------------------------------------------
__global__ void split_kernel(const float* __restrict__ qw, const float* __restrict__ kw,
                             const float* __restrict__ vw, const float* __restrict__ ow,
                             ushort_t* __restrict__ wsplit, ushort_t* __restrict__ osplit)
{
    int i = blockIdx.x * 256 + threadIdx.x;      // 1536*512
    int d = i >> 9, c = i & 511;
    const float* src = (d < 512) ? qw : (d < 1024) ? kw : vw;
    float wv = src[(d & 511) * 512 + c];
    ushort_t h = f2bf(wv);
    float r1 = wv - bf2f(h);
    ushort_t mm = f2bf(r1);
    float r2 = r1 - bf2f(mm);
    ushort_t l = f2bf(r2);                       // h+m+l == wv (within 2^-26)
    wsplit[((size_t)d * 3 + 0) * 512 + c] = h;
    wsplit[((size_t)d * 3 + 1) * 512 + c] = mm;
    wsplit[((size_t)d * 3 + 2) * 512 + c] = l;
    if (d < 512)
        osplit[(size_t)d * 512 + c] = f2bf(ow[d * 512 + c]);
}

// ---------------------------------------------------------------------------
// K1: xs = lif(x), transposed to [m'][c] bf16 spikes, m' = (b*196+n)*4 + t
// ---------------------------------------------------------------------------
__global__ __launch_bounds__(256)
void lifx_kernel(const float* __restrict__ x, ushort_t* __restrict__ xs)
{
    __shared__ ushort_t tile[64 * 66];
    const int tid = threadIdx.x;
    const int b = blockIdx.z, c0 = blockIdx.y * 64, n0 = blockIdx.x * 64;
    const int j = tid & 63, w = tid >> 6;
    const bool nok = (n0 + j) < N_;
    float v[16];
#pragma unroll
    for (int r = 0; r < 16; ++r) v[r] = 0.f;
    for (int t = 0; t < T_; ++t) {
        const float* xb = x + ((size_t)((t * B_ + b) * C_ + c0)) * N_ + n0 + j;
#pragma unroll
        for (int r = 0; r < 16; ++r) {
            int i = w * 16 + r;
            float xv = nok ? xb[(size_t)i * N_] : 0.f;
            v[r] = v[r] + (xv - v[r]) * 0.5f;
            bool s = (v[r] >= 1.0f);
            tile[j * 66 + i] = s ? 0x3F80 : 0;
            if (s) v[r] = 0.f;
        }
        __syncthreads();
#pragma unroll
        for (int p = 0; p < 2; ++p) {
            int w2 = tid + p * 256;
            int jj = w2 >> 3, ck = w2 & 7;
            if (n0 + jj < N_) {
                const unsigned int* src = reinterpret_cast<const unsigned int*>(&tile[jj * 66 + ck * 8]);
                uint4 dv; dv.x = src[0]; dv.y = src[1]; dv.z = src[2]; dv.w = src[3];
                size_t mp = (size_t)(b * N_ + n0 + jj) * 4 + t;      // permuted row
                *reinterpret_cast<uint4*>(&xs[mp * 512 + c0 + ck * 8]) = dv;
            }
        }
        __syncthreads();
    }
}

// ---------------------------------------------------------------------------
// K2: qkv GEMM, 32x32x16 MFMA, 256x128 tile, 3-split exact weights,
// fused BN + LIF epilogue; v-plane blocks also emit vh (out2, fp32).
// A-op = X rows (m' = 4*bn+t), B-op = W rows (d). C/D: col=lane&31,
// row=(reg&3)+8*(reg>>2)+4*(lane>>5) -> t = reg&3, LIF in-register.
// LDS chunks are fragment-linear (lane*16B) -> zero bank conflicts.
// ---------------------------------------------------------------------------
__global__ __launch_bounds__(256, 2)
void qkv_gemm_lif(const ushort_t* __restrict__ W, const ushort_t* __restrict__ X,
                  const float* __restrict__ scale, const float* __restrict__ shift,
                  ushort_t* __restrict__ spk, float* __restrict__ out2)
{
    __shared__ ushort_t Xs[16 * 512];    // 16 chunks of 1KB: [mb(8)][ks(2)]
    __shared__ ushort_t Ws[24 * 512];    // 24 chunks: [s(3)][db(4)][ks(2)]
    const int tid = threadIdx.x, wid = tid >> 6, lane = tid & 63;
    const int m0 = blockIdx.x * 256;     // m' base (256-tile)
    const int d0 = blockIdx.y * 128;     // global d in [0,1536)
    const int mw = (wid & 1) * 128, dw = (wid >> 1) * 64;
    const int row32 = lane & 31, khalf = lane >> 5;

    f32x16 acc[4][2] = {};               // [i: m-block32][j: d-block32]

    for (int k0 = 0; k0 < 512; k0 += 32) {
        __syncthreads();
        for (int q = wid; q < 16; q += 4) {
            int mb = q >> 1, ks = q & 1;
            const ushort_t* g = X + (size_t)(m0 + mb * 32 + row32) * 512 + k0 + ks * 16 + khalf * 8;
            GL2LDS(g, &Xs[q * 512]);
        }
        for (int q = wid; q < 24; q += 4) {
            int s = q >> 3, rem = q & 7, db = rem >> 1, ks = rem & 1;
            const ushort_t* g = W + ((size_t)(d0 + db * 32 + row32) * 3 + s) * 512 + k0 + ks * 16 + khalf * 8;
            GL2LDS(g, &Ws[q * 512]);
        }
        __syncthreads();

#pragma unroll
        for (int ks = 0; ks < 2; ++ks) {
            bf16x8 xfr[4];
#pragma unroll
            for (int i = 0; i < 4; ++i)
                xfr[i] = *reinterpret_cast<const bf16x8*>(&Xs[(((mw >> 5) + i) * 2 + ks) * 512 + lane * 8]);
#pragma unroll
            for (int s = 0; s < 3; ++s)
#pragma unroll
                for (int j = 0; j < 2; ++j) {
                    bf16x8 wfr = *reinterpret_cast<const bf16x8*>(
                        &Ws[(s * 8 + ((dw >> 5) + j) * 2 + ks) * 512 + lane * 8]);
#pragma unroll
                    for (int i = 0; i < 4; ++i)
                        acc[i][j] = __builtin_amdgcn_mfma_f32_32x32x16_bf16(xfr[i], wfr, acc[i][j], 0, 0, 0);
                }
        }
    }

    // epilogue: BN -> LIF over t (reg&3) -> bf16 spike planes [t][bn][c];
    // v-plane additionally writes out2[t][b][h][n][hd] fp32
    const int p = d0 >> 9;
    const bool isV = (p == 2);
    ushort_t* plane = spk + (size_t)p * ((size_t)M_ * 512);
#pragma unroll
    for (int j = 0; j < 2; ++j) {
        int d = d0 + dw + j * 32 + row32;
        float sc = scale[d], sh = shift[d];
        int dl = d & 511;
        int h = dl >> 6, hd = dl & 63;
#pragma unroll
        for (int i = 0; i < 4; ++i) {
            int bnb = (m0 + mw + i * 32) >> 2;
            f32x16 a = acc[i][j];
#pragma unroll
            for (int g = 0; g < 4; ++g) {
                int bn = bnb + 2 * g + khalf;
                float p0 = fmaf(a[4 * g + 0], sc, sh);
                float p1 = fmaf(a[4 * g + 1], sc, sh);
                float p2 = fmaf(a[4 * g + 2], sc, sh);
                float p3 = fmaf(a[4 * g + 3], sc, sh);
                float v = p0 * 0.5f;
                bool s0 = (v >= 1.f); if (s0) v = 0.f;
                v = v + (p1 - v) * 0.5f;
                bool s1 = (v >= 1.f); if (s1) v = 0.f;
                v = v + (p2 - v) * 0.5f;
                bool s2 = (v >= 1.f); if (s2) v = 0.f;
                v = v + (p3 - v) * 0.5f;
                bool s3 = (v >= 1.f);
                ushort_t* b0 = plane + (size_t)bn * 512 + dl;
                b0[0]                      = s0 ? 0x3F80 : 0;
                b0[(size_t)BNP_ * 512]     = s1 ? 0x3F80 : 0;
                b0[(size_t)2 * BNP_ * 512] = s2 ? 0x3F80 : 0;
                b0[(size_t)3 * BNP_ * 512] = s3 ? 0x3F80 : 0;
                if (isV) {
                    int b = bn / N_, n = bn - b * N_;
                    float* o = out2 + (((size_t)b * 8 + h) * N_ + n) * 64 + hd;
                    o[0]                       = s0 ? 1.f : 0.f;
                    o[(size_t)1 * (OUT1_ / 4)] = s1 ? 1.f : 0.f;
                    o[(size_t)2 * (OUT1_ / 4)] = s2 ? 1.f : 0.f;
                    o[(size_t)3 * (OUT1_ / 4)] = s3 ? 1.f : 0.f;
                }
            }
        }
    }
}

// ---------------------------------------------------------------------------
// K3: kvpart[tb][c] = sum_n (k_s & v_s)  (exact integer count)
// ---------------------------------------------------------------------------
__global__ void kv_part_kernel(const ushort_t* __restrict__ ks, const ushort_t* __restrict__ vs,
                               float* __restrict__ kvpart)
{
    int tb = blockIdx.x >> 1;
    int c  = (blockIdx.x & 1) * 256 + threadIdx.x;
    const ushort_t* kb = ks + (size_t)tb * N_ * 512 + c;
    const ushort_t* vb = vs + (size_t)tb * N_ * 512 + c;
    int cnt = 0;
    for (int n = 0; n < N_; ++n)
        cnt += (kb[(size_t)n * 512] & vb[(size_t)n * 512]) ? 1 : 0;
    kvpart[tb * 512 + c] = (float)cnt;
}

// ---------------------------------------------------------------------------
// K4: LIF over t on kvpart -> kv spikes bf16 [tb][c]
// ---------------------------------------------------------------------------
__global__ void kv_lif_kernel(const float* __restrict__ kvpart, ushort_t* __restrict__ kvs)
{
    int i = blockIdx.x * 256 + threadIdx.x;      // 32*512
    if (i >= B_ * C_) return;
    int b = i >> 9, c = i & 511;
    float v = 0.f;
#pragma unroll
    for (int t = 0; t < T_; ++t) {
        float y = kvpart[((t * B_ + b) << 9) + c];
        v = v + (y - v) * 0.5f;
        bool s = (v >= 1.f);
        kvs[((t * B_ + b) << 9) + c] = s ? 0x3F80 : 0;
        if (s) v = 0.f;
    }
}

// ---------------------------------------------------------------------------
// K5: y[m][c] = q_s[m][c] & kvs[tb][c]   (pure AND of spike bit patterns)
// ---------------------------------------------------------------------------
__global__ void muly_kernel(const ushort_t* __restrict__ qs, const ushort_t* __restrict__ kvs,
                            ushort_t* __restrict__ y)
{
    int i = blockIdx.x * 256 + threadIdx.x;      // uint4 (8-short) units
    int m = i >> 6, cq = (i & 63) * 8;
    int tb = m / N_;
    uint4 q = *reinterpret_cast<const uint4*>(&qs[(size_t)m * 512 + cq]);
    uint4 k = *reinterpret_cast<const uint4*>(&kvs[(size_t)tb * 512 + cq]);
    uint4 o; o.x = q.x & k.x; o.y = q.y & k.y; o.z = q.z & k.z; o.w = q.w & k.w;
    *reinterpret_cast<uint4*>(&y[(size_t)m * 512 + cq]) = o;
}

// ---------------------------------------------------------------------------
// K6: out GEMM, 32x32x16 MFMA, 128x128 tile. A-op = out weights (rows d),
// B-op = y (rows m). Epilogue: BN+bias + identity; 32-lane-contiguous-n
// stores -> full 128B lines.
// ---------------------------------------------------------------------------
__global__ __launch_bounds__(256)
void out_gemm(const ushort_t* __restrict__ A, const ushort_t* __restrict__ Bm,
              const float* __restrict__ scale, const float* __restrict__ shift,
              const float* __restrict__ xid, float* __restrict__ out)
{
    __shared__ ushort_t As[8 * 512];     // [db(4)][ks(2)]
    __shared__ ushort_t Bs[8 * 512];     // [mb(4)][ks(2)]
    const int tid = threadIdx.x, wid = tid >> 6, lane = tid & 63;
    const int d0 = blockIdx.y * 128, m0 = blockIdx.x * 128;
    const int dw = (wid >> 1) * 64, mw = (wid & 1) * 64;
    const int row32 = lane & 31, khalf = lane >> 5;

    f32x16 acc[2][2] = {};               // [i: d-block32][j: m-block32]

    for (int k0 = 0; k0 < 512; k0 += 32) {
        __syncthreads();
        for (int q = wid; q < 8; q += 4) {
            int db = q >> 1, ks = q & 1;
            const ushort_t* g = A + (size_t)(d0 + db * 32 + row32) * 512 + k0 + ks * 16 + khalf * 8;
            GL2LDS(g, &As[q * 512]);
        }
        for (int q = wid; q < 8; q += 4) {
            int mb = q >> 1, ks = q & 1;
            const ushort_t* g = Bm + (size_t)(m0 + mb * 32 + row32) * 512 + k0 + ks * 16 + khalf * 8;
            GL2LDS(g, &Bs[q * 512]);
        }
        __syncthreads();

#pragma unroll
        for (int ks = 0; ks < 2; ++ks) {
            bf16x8 afr[2];
#pragma unroll
            for (int i = 0; i < 2; ++i)
                afr[i] = *reinterpret_cast<const bf16x8*>(&As[(((dw >> 5) + i) * 2 + ks) * 512 + lane * 8]);
#pragma unroll
            for (int j = 0; j < 2; ++j) {
                bf16x8 bfr = *reinterpret_cast<const bf16x8*>(&Bs[(((mw >> 5) + j) * 2 + ks) * 512 + lane * 8]);
#pragma unroll
                for (int i = 0; i < 2; ++i)
                    acc[i][j] = __builtin_amdgcn_mfma_f32_32x32x16_bf16(afr[i], bfr, acc[i][j], 0, 0, 0);
            }
        }
    }

#pragma unroll
    for (int j = 0; j < 2; ++j) {
        int m = m0 + mw + j * 32 + row32;     // col = m (n contiguous across lanes)
        int tb = m / N_;
        int n  = m - tb * N_;
        size_t mbase = (size_t)tb * (C_ * N_) + n;
#pragma unroll
        for (int i = 0; i < 2; ++i) {
            int dbase = d0 + dw + i * 32 + 4 * khalf;
            f32x16 a = acc[i][j];
#pragma unroll
            for (int g = 0; g < 4; ++g) {
#pragma unroll
                for (int t = 0; t < 4; ++t) {
                    int d = dbase + t + 8 * g;
                    float val = fmaf(a[4 * g + t], scale[d], shift[d]);
                    size_t ad = mbase + (size_t)d * N_;
                    out[ad] = val + xid[ad];
                }
            }
        }
    }
}

// ---------------------------------------------------------------------------
extern "C" void kernel_launch(void* const* d_in, const int* in_sizes, int n_in,
                              void* d_out, int out_size, void* d_ws, size_t ws_size,
                              hipStream_t stream)
{
    const float* x    = (const float*)d_in[0];
    const float* q_w  = (const float*)d_in[1];
    const float* k_w  = (const float*)d_in[2];
    const float* v_w  = (const float*)d_in[3];
    const float* o_w  = (const float*)d_in[4];
    const float* o_b  = (const float*)d_in[5];
    const float* qg = (const float*)d_in[6],  *qb = (const float*)d_in[7],
               *qm = (const float*)d_in[8],  *qv = (const float*)d_in[9];
    const float* kg = (const float*)d_in[10], *kb = (const float*)d_in[11],
               *km = (const float*)d_in[12], *kv = (const float*)d_in[13];
    const float* vg = (const float*)d_in[14], *vb = (const float*)d_in[15],
               *vm = (const float*)d_in[16], *vv = (const float*)d_in[17];
    const float* og = (const float*)d_in[18], *ob = (const float*)d_in[19],
               *om = (const float*)d_in[20], *ov = (const float*)d_in[21];

    float* out1  = (float*)d_out;
    float* out2f = out1 + OUT1_;

    // d_ws layout (all scratch lives here now; out2 is written only by qkv)
    ushort_t* spk    = (ushort_t*)d_ws;                      // [3][M][512] bf16 spikes
    ushort_t* xs     = spk + (size_t)3 * M_ * 512;           // [M][512] bf16 (m' order); reused as y
    ushort_t* wsplit = xs + (size_t)M_ * 512;                // 1536*3*512
    ushort_t* osplit = wsplit + (size_t)1536 * 3 * 512;      // 512*512
    float*    kvpart = (float*)(osplit + (size_t)512 * 512); // [TB][C]
    ushort_t* kvs    = (ushort_t*)(kvpart + TB_ * C_);       // [TB][C]
    float*    scq    = (float*)(kvs + TB_ * C_);
    float*    shq    = scq + 3 * C_;
    float*    sco    = shq + 3 * C_;
    float*    sho    = sco + C_;

    ushort_t* ksp = spk + (size_t)M_ * 512;
    ushort_t* vsp = spk + (size_t)2 * M_ * 512;

    bn_prep_kernel<<<8, 256, 0, stream>>>(qg, qb, qm, qv, kg, kb, km, kv,
                                          vg, vb, vm, vv, og, ob, om, ov, o_b,
                                          scq, shq, sco, sho);

    split_kernel<<<(1536 * 512) / 256, 256, 0, stream>>>(q_w, k_w, v_w, o_w, wsplit, osplit);

    lifx_kernel<<<dim3(4, 8, 32), 256, 0, stream>>>(x, xs);

    qkv_gemm_lif<<<dim3(98, 12), 256, 0, stream>>>(wsplit, xs, scq, shq, spk, out2f);

    kv_part_kernel<<<256, 256, 0, stream>>>(ksp, vsp, kvpart);

    kv_lif_kernel<<<64, 256, 0, stream>>>(kvpart, kvs);

    muly_kernel<<<(M_ * 64) / 256, 256, 0, stream>>>(spk, kvs, xs /* reused as y */);

    out_gemm<<<dim3(196, 4), 256, 0, stream>>>(osplit, xs, sco, sho, x, out1);
}

// Round 6
// 407.387 us; speedup vs baseline: 2.3763x; 1.1066x over previous
//
#include <hip/hip_runtime.h>
#include <math.h>

#define T_   4
#define B_   32
#define C_   512
#define N_   196
#define TB_  128
#define M_   25088          // TB_*N_
#define BNP_ 6272           // B_*N_  (t-plane stride in bn-space)
#define OUT1_ 12845056      // T_*B_*C_*N_

typedef unsigned short ushort_t;
typedef __attribute__((ext_vector_type(8)))  __bf16 bf16x8;
typedef __attribute__((ext_vector_type(16))) float  f32x16;

__device__ __forceinline__ ushort_t f2bf(float f) {
    unsigned int u = __float_as_uint(f);
    u = u + 0x7FFFu + ((u >> 16) & 1u);      // RN-even
    return (ushort_t)(u >> 16);
}
__device__ __forceinline__ float bf2f(ushort_t h) {
    return __uint_as_float(((unsigned int)h) << 16);
}

#define GL2LDS(gp, lp) \
    __builtin_amdgcn_global_load_lds((const __attribute__((address_space(1))) void*)(gp), \
                                     (__attribute__((address_space(3))) void*)(lp), 16, 0, 0)

// ---------------------------------------------------------------------------
// K0: prep — BN fold, 2-way bf16 weight split (err ~2e-6 RMS in preact,
// below fp32-reorder noise proven safe in round 1), bf16 out weights,
// and zero kvpart (atomicAdd target).
// ---------------------------------------------------------------------------
__global__ void prep_kernel(
    const float* __restrict__ qw, const float* __restrict__ kw,
    const float* __restrict__ vw, const float* __restrict__ ow,
    const float* __restrict__ qg, const float* __restrict__ qb, const float* __restrict__ qm, const float* __restrict__ qv,
    const float* __restrict__ kg, const float* __restrict__ kb, const float* __restrict__ km, const float* __restrict__ kvr,
    const float* __restrict__ vg, const float* __restrict__ vb, const float* __restrict__ vm, const float* __restrict__ vv,
    const float* __restrict__ og, const float* __restrict__ ob, const float* __restrict__ om, const float* __restrict__ ov,
    const float* __restrict__ obias,
    ushort_t* __restrict__ wsplit, ushort_t* __restrict__ osplit,
    float* __restrict__ scale_qkv, float* __restrict__ shift_qkv,
    float* __restrict__ scale_o,   float* __restrict__ shift_o,
    float* __restrict__ kvpart)
{
    int i = blockIdx.x * 256 + threadIdx.x;      // [0, 1536*512)
    int d = i >> 9, c = i & 511;
    const float* src = (d < 512) ? qw : (d < 1024) ? kw : vw;
    float wv = src[(d & 511) * 512 + c];
    ushort_t h = f2bf(wv);
    float r1 = wv - bf2f(h);
    ushort_t mm = f2bf(r1);
    wsplit[((size_t)d * 2 + 0) * 512 + c] = h;
    wsplit[((size_t)d * 2 + 1) * 512 + c] = mm;
    if (d < 512)
        osplit[(size_t)d * 512 + c] = f2bf(ow[d * 512 + c]);

    if (i < 3 * C_) {
        int p = i >> 9, dl = i & 511;
        const float* g = (p == 0) ? qg : (p == 1) ? kg : vg;
        const float* b = (p == 0) ? qb : (p == 1) ? kb : vb;
        const float* m = (p == 0) ? qm : (p == 1) ? km : vm;
        const float* r = (p == 0) ? qv : (p == 1) ? kvr : vv;
        float sc = g[dl] / sqrtf(r[dl] + 1e-5f);
        scale_qkv[i] = sc;
        shift_qkv[i] = b[dl] - m[dl] * sc;
    }
    if (i < C_) {
        float sc = og[i] / sqrtf(ov[i] + 1e-5f);
        scale_o[i] = sc;
        shift_o[i] = ob[i] - om[i] * sc + obias[i] * sc;
    }
    if (i < TB_ * C_) kvpart[i] = 0.f;
}

// ---------------------------------------------------------------------------
// K1: xs = lif(x), transposed to [m'][c] bf16 spikes, m' = (b*196+n)*4 + t
// ---------------------------------------------------------------------------
__global__ __launch_bounds__(256)
void lifx_kernel(const float* __restrict__ x, ushort_t* __restrict__ xs)
{
    __shared__ ushort_t tile[64 * 66];
    const int tid = threadIdx.x;
    const int b = blockIdx.z, c0 = blockIdx.y * 64, n0 = blockIdx.x * 64;
    const int j = tid & 63, w = tid >> 6;
    const bool nok = (n0 + j) < N_;
    float v[16];
#pragma unroll
    for (int r = 0; r < 16; ++r) v[r] = 0.f;
    for (int t = 0; t < T_; ++t) {
        const float* xb = x + ((size_t)((t * B_ + b) * C_ + c0)) * N_ + n0 + j;
#pragma unroll
        for (int r = 0; r < 16; ++r) {
            int i = w * 16 + r;
            float xv = nok ? xb[(size_t)i * N_] : 0.f;
            v[r] = v[r] + (xv - v[r]) * 0.5f;
            bool s = (v[r] >= 1.0f);
            tile[j * 66 + i] = s ? 0x3F80 : 0;
            if (s) v[r] = 0.f;
        }
        __syncthreads();
#pragma unroll
        for (int p = 0; p < 2; ++p) {
            int w2 = tid + p * 256;
            int jj = w2 >> 3, ck = w2 & 7;
            if (n0 + jj < N_) {
                const unsigned int* src = reinterpret_cast<const unsigned int*>(&tile[jj * 66 + ck * 8]);
                uint4 dv; dv.x = src[0]; dv.y = src[1]; dv.z = src[2]; dv.w = src[3];
                size_t mp = (size_t)(b * N_ + n0 + jj) * 4 + t;      // permuted row
                *reinterpret_cast<uint4*>(&xs[mp * 512 + c0 + ck * 8]) = dv;
            }
        }
        __syncthreads();
    }
}

// ---------------------------------------------------------------------------
// K2: qkv GEMM, 32x32x16 MFMA, 256x128 tile, 2-split weights,
// fused BN + LIF epilogue; v-plane also emits vh (out2, fp32).
// XCD swizzle: xcd = id%8 (round-robin heuristic); per XCD, m-major so the
// full 2-split W (3.1 MB) goes L2-resident while the XCD's X slab streams.
// ---------------------------------------------------------------------------
__global__ __launch_bounds__(256, 2)
void qkv_gemm_lif(const ushort_t* __restrict__ W, const ushort_t* __restrict__ X,
                  const float* __restrict__ scale, const float* __restrict__ shift,
                  ushort_t* __restrict__ spk, float* __restrict__ out2)
{
    const int id = blockIdx.x;
    const int xw = id & 7, local = id >> 3;      // local in [0,150)
    const int ml = local / 12, d_t = local - ml * 12;
    const int m_t = ml * 8 + xw;
    if (m_t >= 98) return;
    const int m0 = m_t * 256;                    // m' base (256-tile)
    const int d0 = d_t * 128;                    // global d in [0,1536)

    __shared__ ushort_t Xs[16 * 512];    // 16 chunks of 1KB: [mb(8)][ks(2)]
    __shared__ ushort_t Ws[16 * 512];    // 16 chunks: [s(2)][db(4)][ks(2)]
    const int tid = threadIdx.x, wid = tid >> 6, lane = tid & 63;
    const int mw = (wid & 1) * 128, dw = (wid >> 1) * 64;
    const int row32 = lane & 31, khalf = lane >> 5;

    f32x16 acc[4][2] = {};               // [i: m-block32][j: d-block32]

    for (int k0 = 0; k0 < 512; k0 += 32) {
        __syncthreads();
        for (int q = wid; q < 16; q += 4) {
            int mb = q >> 1, ks = q & 1;
            const ushort_t* g = X + (size_t)(m0 + mb * 32 + row32) * 512 + k0 + ks * 16 + khalf * 8;
            GL2LDS(g, &Xs[q * 512]);
        }
        for (int q = wid; q < 16; q += 4) {
            int s = q >> 3, rem = q & 7, db = rem >> 1, ks = rem & 1;
            const ushort_t* g = W + ((size_t)(d0 + db * 32 + row32) * 2 + s) * 512 + k0 + ks * 16 + khalf * 8;
            GL2LDS(g, &Ws[q * 512]);
        }
        __syncthreads();

#pragma unroll
        for (int ks = 0; ks < 2; ++ks) {
            bf16x8 xfr[4];
#pragma unroll
            for (int i = 0; i < 4; ++i)
                xfr[i] = *reinterpret_cast<const bf16x8*>(&Xs[(((mw >> 5) + i) * 2 + ks) * 512 + lane * 8]);
#pragma unroll
            for (int s = 0; s < 2; ++s)
#pragma unroll
                for (int j = 0; j < 2; ++j) {
                    bf16x8 wfr = *reinterpret_cast<const bf16x8*>(
                        &Ws[(s * 8 + ((dw >> 5) + j) * 2 + ks) * 512 + lane * 8]);
#pragma unroll
                    for (int i = 0; i < 4; ++i)
                        acc[i][j] = __builtin_amdgcn_mfma_f32_32x32x16_bf16(xfr[i], wfr, acc[i][j], 0, 0, 0);
                }
        }
    }

    // epilogue: BN -> LIF over t (reg&3) -> bf16 spike planes [t][bn][c];
    // v-plane additionally writes out2[t][b][h][n][hd] fp32
    const int p = d0 >> 9;
    const bool isV = (p == 2);
    ushort_t* plane = spk + (size_t)p * ((size_t)M_ * 512);
#pragma unroll
    for (int j = 0; j < 2; ++j) {
        int d = d0 + dw + j * 32 + row32;
        float sc = scale[d], sh = shift[d];
        int dl = d & 511;
        int h = dl >> 6, hd = dl & 63;
#pragma unroll
    for (int i = 0; i < 4; ++i) {
            int bnb = (m0 + mw + i * 32) >> 2;
            f32x16 a = acc[i][j];
#pragma unroll
            for (int g = 0; g < 4; ++g) {
                int bn = bnb + 2 * g + khalf;
                float p0 = fmaf(a[4 * g + 0], sc, sh);
                float p1 = fmaf(a[4 * g + 1], sc, sh);
                float p2 = fmaf(a[4 * g + 2], sc, sh);
                float p3 = fmaf(a[4 * g + 3], sc, sh);
                float v = p0 * 0.5f;
                bool s0 = (v >= 1.f); if (s0) v = 0.f;
                v = v + (p1 - v) * 0.5f;
                bool s1 = (v >= 1.f); if (s1) v = 0.f;
                v = v + (p2 - v) * 0.5f;
                bool s2 = (v >= 1.f); if (s2) v = 0.f;
                v = v + (p3 - v) * 0.5f;
                bool s3 = (v >= 1.f);
                ushort_t* b0 = plane + (size_t)bn * 512 + dl;
                b0[0]                      = s0 ? 0x3F80 : 0;
                b0[(size_t)BNP_ * 512]     = s1 ? 0x3F80 : 0;
                b0[(size_t)2 * BNP_ * 512] = s2 ? 0x3F80 : 0;
                b0[(size_t)3 * BNP_ * 512] = s3 ? 0x3F80 : 0;
                if (isV) {
                    int b = bn / N_, n = bn - b * N_;
                    float* o = out2 + (((size_t)b * 8 + h) * N_ + n) * 64 + hd;
                    o[0]                       = s0 ? 1.f : 0.f;
                    o[(size_t)1 * (OUT1_ / 4)] = s1 ? 1.f : 0.f;
                    o[(size_t)2 * (OUT1_ / 4)] = s2 ? 1.f : 0.f;
                    o[(size_t)3 * (OUT1_ / 4)] = s3 ? 1.f : 0.f;
                }
            }
        }
    }
}

// ---------------------------------------------------------------------------
// K3: kvpart[tb][c] += sum_n (k_s & v_s) over an n-chunk (exact int atomics)
// grid 1024: id -> tb (128) x cb (2) x nh (4)
// ---------------------------------------------------------------------------
__global__ void kv_part_kernel(const ushort_t* __restrict__ ks, const ushort_t* __restrict__ vs,
                               float* __restrict__ kvpart)
{
    int id = blockIdx.x;
    int tb = id >> 3, r = id & 7;
    int c  = (r & 1) * 256 + threadIdx.x;
    int n0 = (r >> 1) * 49;
    const ushort_t* kb = ks + (size_t)tb * N_ * 512 + c;
    const ushort_t* vb = vs + (size_t)tb * N_ * 512 + c;
    int cnt = 0;
    for (int n = n0; n < n0 + 49; ++n)
        cnt += (kb[(size_t)n * 512] & vb[(size_t)n * 512]) ? 1 : 0;
    atomicAdd(&kvpart[tb * 512 + c], (float)cnt);
}

// ---------------------------------------------------------------------------
// K4: LIF over t on kvpart -> kv spikes bf16 [tb][c]
// ---------------------------------------------------------------------------
__global__ void kv_lif_kernel(const float* __restrict__ kvpart, ushort_t* __restrict__ kvs)
{
    int i = blockIdx.x * 256 + threadIdx.x;      // 32*512
    if (i >= B_ * C_) return;
    int b = i >> 9, c = i & 511;
    float v = 0.f;
#pragma unroll
    for (int t = 0; t < T_; ++t) {
        float y = kvpart[((t * B_ + b) << 9) + c];
        v = v + (y - v) * 0.5f;
        bool s = (v >= 1.f);
        kvs[((t * B_ + b) << 9) + c] = s ? 0x3F80 : 0;
        if (s) v = 0.f;
    }
}

// ---------------------------------------------------------------------------
// K6: out GEMM with fused muly: B-tile staged as (q_s & kvs) via VALU+ds_write
// (bitwise AND of 0x3F80 spike patterns). 32x32x16 MFMA, 128x128 tile,
// XCD swizzle m-major. Epilogue: BN+bias + identity.
// ---------------------------------------------------------------------------
__global__ __launch_bounds__(256)
void out_gemm(const ushort_t* __restrict__ A, const ushort_t* __restrict__ qs,
              const ushort_t* __restrict__ kvs,
              const float* __restrict__ scale, const float* __restrict__ shift,
              const float* __restrict__ xid, float* __restrict__ out)
{
    const int id = blockIdx.x;
    const int xw = id & 7, local = id >> 3;      // local < 100
    const int m_t = (local >> 2) * 8 + xw, d_t = local & 3;
    if (m_t >= 196) return;
    const int m0 = m_t * 128, d0 = d_t * 128;

    __shared__ ushort_t As[8 * 512];     // [db(4)][ks(2)]
    __shared__ ushort_t Bs[8 * 512];     // [mb(4)][ks(2)]
    const int tid = threadIdx.x, wid = tid >> 6, lane = tid & 63;
    const int dw = (wid >> 1) * 64, mw = (wid & 1) * 64;
    const int row32 = lane & 31, khalf = lane >> 5;

    // per-thread B-staging slots (constant across K-loop)
    int sm[2], stb[2], sq[2], sL[2];
#pragma unroll
    for (int u = 0; u < 2; ++u) {
        int s = tid + u * 256;
        sq[u] = s >> 6; sL[u] = s & 63;
        sm[u] = m0 + (sq[u] >> 1) * 32 + (sL[u] & 31);
        stb[u] = sm[u] / N_;
    }

    f32x16 acc[2][2] = {};               // [i: d-block32][j: m-block32]

    for (int k0 = 0; k0 < 512; k0 += 32) {
        __syncthreads();
        for (int q = wid; q < 8; q += 4) {
            int db = q >> 1, ks = q & 1;
            const ushort_t* g = A + (size_t)(d0 + db * 32 + row32) * 512 + k0 + ks * 16 + khalf * 8;
            GL2LDS(g, &As[q * 512]);
        }
#pragma unroll
        for (int u = 0; u < 2; ++u) {
            int kk = k0 + (sq[u] & 1) * 16 + (sL[u] >> 5) * 8;
            uint4 qv = *reinterpret_cast<const uint4*>(&qs[(size_t)sm[u] * 512 + kk]);
            uint4 kv = *reinterpret_cast<const uint4*>(&kvs[(size_t)stb[u] * 512 + kk]);
            uint4 o; o.x = qv.x & kv.x; o.y = qv.y & kv.y; o.z = qv.z & kv.z; o.w = qv.w & kv.w;
            *reinterpret_cast<uint4*>(&Bs[sq[u] * 512 + sL[u] * 8]) = o;
        }
        __syncthreads();

#pragma unroll
        for (int ks = 0; ks < 2; ++ks) {
            bf16x8 afr[2];
#pragma unroll
            for (int i = 0; i < 2; ++i)
                afr[i] = *reinterpret_cast<const bf16x8*>(&As[(((dw >> 5) + i) * 2 + ks) * 512 + lane * 8]);
#pragma unroll
            for (int j = 0; j < 2; ++j) {
                bf16x8 bfr = *reinterpret_cast<const bf16x8*>(&Bs[(((mw >> 5) + j) * 2 + ks) * 512 + lane * 8]);
#pragma unroll
                for (int i = 0; i < 2; ++i)
                    acc[i][j] = __builtin_amdgcn_mfma_f32_32x32x16_bf16(afr[i], bfr, acc[i][j], 0, 0, 0);
            }
        }
    }

#pragma unroll
    for (int j = 0; j < 2; ++j) {
        int m = m0 + mw + j * 32 + row32;     // n contiguous across lanes
        int tb = m / N_;
        int n  = m - tb * N_;
        size_t mbase = (size_t)tb * (C_ * N_) + n;
#pragma unroll
        for (int i = 0; i < 2; ++i) {
            int dbase = d0 + dw + i * 32 + 4 * khalf;
            f32x16 a = acc[i][j];
#pragma unroll
            for (int g = 0; g < 4; ++g) {
#pragma unroll
                for (int t = 0; t < 4; ++t) {
                    int d = dbase + t + 8 * g;
                    float val = fmaf(a[4 * g + t], scale[d], shift[d]);
                    size_t ad = mbase + (size_t)d * N_;
                    out[ad] = val + xid[ad];
                }
            }
        }
    }
}

// ---------------------------------------------------------------------------
extern "C" void kernel_launch(void* const* d_in, const int* in_sizes, int n_in,
                              void* d_out, int out_size, void* d_ws, size_t ws_size,
                              hipStream_t stream)
{
    const float* x    = (const float*)d_in[0];
    const float* q_w  = (const float*)d_in[1];
    const float* k_w  = (const float*)d_in[2];
    const float* v_w  = (const float*)d_in[3];
    const float* o_w  = (const float*)d_in[4];
    const float* o_b  = (const float*)d_in[5];
    const float* qg = (const float*)d_in[6],  *qb = (const float*)d_in[7],
               *qm = (const float*)d_in[8],  *qv = (const float*)d_in[9];
    const float* kg = (const float*)d_in[10], *kb = (const float*)d_in[11],
               *km = (const float*)d_in[12], *kv = (const float*)d_in[13];
    const float* vg = (const float*)d_in[14], *vb = (const float*)d_in[15],
               *vm = (const float*)d_in[16], *vv = (const float*)d_in[17];
    const float* og = (const float*)d_in[18], *ob = (const float*)d_in[19],
               *om = (const float*)d_in[20], *ov = (const float*)d_in[21];

    float* out1  = (float*)d_out;
    float* out2f = out1 + OUT1_;

    // d_ws layout
    ushort_t* spk    = (ushort_t*)d_ws;                      // [3][M][512] bf16 spikes
    ushort_t* xs     = spk + (size_t)3 * M_ * 512;           // [M][512] bf16 (m' order)
    ushort_t* wsplit = xs + (size_t)M_ * 512;                // 1536*2*512
    ushort_t* osplit = wsplit + (size_t)1536 * 2 * 512;      // 512*512
    float*    kvpart = (float*)(osplit + (size_t)512 * 512); // [TB][C]
    ushort_t* kvs    = (ushort_t*)(kvpart + TB_ * C_);       // [TB][C]
    float*    scq    = (float*)(kvs + TB_ * C_);
    float*    shq    = scq + 3 * C_;
    float*    sco    = shq + 3 * C_;
    float*    sho    = sco + C_;

    ushort_t* qsp = spk;
    ushort_t* ksp = spk + (size_t)M_ * 512;
    ushort_t* vsp = spk + (size_t)2 * M_ * 512;

    prep_kernel<<<(1536 * 512) / 256, 256, 0, stream>>>(
        q_w, k_w, v_w, o_w,
        qg, qb, qm, qv, kg, kb, km, kv, vg, vb, vm, vv, og, ob, om, ov, o_b,
        wsplit, osplit, scq, shq, sco, sho, kvpart);

    lifx_kernel<<<dim3(4, 8, 32), 256, 0, stream>>>(x, xs);

    qkv_gemm_lif<<<1200, 256, 0, stream>>>(wsplit, xs, scq, shq, spk, out2f);

    kv_part_kernel<<<1024, 256, 0, stream>>>(ksp, vsp, kvpart);

    kv_lif_kernel<<<64, 256, 0, stream>>>(kvpart, kvs);

    out_gemm<<<800, 256, 0, stream>>>(osplit, qsp, kvs, sco, sho, x, out1);
}